// Round 13
// baseline (174.907 us; speedup 1.0000x reference)
//
#include <hip/hip_runtime.h>
#include <math.h>

#define B 128
#define T 2048
#define H 200
#define G4 800    // 4*H
#define KP 224    // Uab row stride (bf16)
#define ESTR 224  // elds row stride (bf16) = KP (R0-proven)
#define ROWS 32   // t-rows per block (halved vs R0 -> 6 blocks/CU)

typedef short short8 __attribute__((ext_vector_type(8)));
typedef float floatx4 __attribute__((ext_vector_type(4)));

__device__ __forceinline__ unsigned short f2bf(float x) {
    unsigned u = __float_as_uint(x);
    return (unsigned short)((u + 0x7fffu + ((u >> 16) & 1u)) >> 16);
}
__device__ __forceinline__ float bf2f(unsigned short s) {
    return __uint_as_float(((unsigned)s) << 16);
}
// pack two floats -> two bf16 (round-nearest-away) in 3 VALU ops
__device__ __forceinline__ unsigned pk2(float a, float b) {
    return __builtin_amdgcn_perm(__float_as_uint(b) + 0x8000u,
                                 __float_as_uint(a) + 0x8000u, 0x07060302u);
}
// tanh(x) = 1 - 2/(exp(2x)+1), hw exp2 + rcp (~1e-6 rel err)
__device__ __forceinline__ float ftanh(float x) {
    float e = __builtin_amdgcn_exp2f(x * 2.885390081777927f);
    float r = __builtin_amdgcn_rcpf(e + 1.f);
    return fmaf(-2.f, r, 1.f);
}
__device__ __forceinline__ float sigm(float x) { return 1.f / (1.f + expf(-x)); }

// ---------------- prep_all ----------------
// blocks 0..255    : Uab row (bf16, zero-padded [256][224])
// blocks 256..455  : W_ihT[k][j] = W_ih[j][1+k]
// blocks 456..655  : W_hhT[k][j] = W_hh[j][k]
// block  656       : wx[j] = W_ih[j][0]
// blocks 657..784  : qb[b][h] = h0[b] @ Wa.T + ba + bua   (float4 dot)
// blocks 785..984  : W1T[k][j] = W1[j][k]   (k<200, j<100)
// blocks 985..1084 : W2T[k][j] = W2[j][k]   (k<100, j<50)
__global__ __launch_bounds__(256) void prep_all(const float* __restrict__ Ua,
                                                const float* __restrict__ Wa,
                                                const float* __restrict__ ba,
                                                const float* __restrict__ bua,
                                                const float* __restrict__ h0,
                                                const float* __restrict__ W_ih,
                                                const float* __restrict__ W_hh,
                                                const float* __restrict__ W1,
                                                const float* __restrict__ W2,
                                                unsigned short* __restrict__ Uab,
                                                float* __restrict__ WihT,
                                                float* __restrict__ WhhT,
                                                float* __restrict__ wx,
                                                float* __restrict__ qb,
                                                float* __restrict__ W1T,
                                                float* __restrict__ W2T) {
    __shared__ __align__(16) float qs[H];
    int bx = blockIdx.x, tid = threadIdx.x;
    if (bx < 256) {
        if (tid < KP) {
            float v = (bx < H && tid < H) ? Ua[bx * H + tid] : 0.f;
            Uab[bx * KP + tid] = f2bf(v);
        }
    } else if (bx < 456) {
        int k = bx - 256;
        for (int j = tid; j < G4; j += 256) WihT[k * G4 + j] = W_ih[(size_t)j * (H + 1) + 1 + k];
    } else if (bx < 656) {
        int k = bx - 456;
        for (int j = tid; j < G4; j += 256) WhhT[k * G4 + j] = W_hh[(size_t)j * H + k];
    } else if (bx == 656) {
        for (int j = tid; j < G4; j += 256) wx[j] = W_ih[(size_t)j * (H + 1)];
    } else if (bx < 785) {
        int b = bx - 657;
        if (tid < H) qs[tid] = h0[b * H + tid];
        __syncthreads();
        if (tid < H) {
            float a = ba[tid] + bua[tid];
            const float4* w  = (const float4*)(Wa + tid * H);
            const float4* qv = (const float4*)qs;
            #pragma unroll 8
            for (int k = 0; k < 50; k++) {
                float4 wv = w[k], q4 = qv[k];
                a = fmaf(wv.x, q4.x, a);
                a = fmaf(wv.y, q4.y, a);
                a = fmaf(wv.z, q4.z, a);
                a = fmaf(wv.w, q4.w, a);
            }
            qb[b * H + tid] = a;
        }
    } else if (bx < 985) {
        int k = bx - 785;
        if (tid < 100) W1T[k * 100 + tid] = W1[tid * H + k];
    } else {
        int k = bx - 985;
        if (tid < 50) W2T[k * 50 + tid] = W2[tid * 100 + k];
    }
}

// ---------------- scores + bounded-softmax + context ----------------
// R0's exact register/structure shape (rolled 2-iteration mig loop, af[2][7]
// reloaded per group, 16 m-tiles, prefetch-by-1 loop staging) -- the ONLY form
// measured spill-free at 64 VGPR across 12 rounds -- at HALF the tile size:
// ROWS=32 -> ~17 KB LDS -> 6 blocks/CU at launch_bounds(256,6) (24 waves/CU,
// +50% TLP vs R0's 43%). Clean A/B on "is TLP the lever at a clean register
// shape": every prior high-occupancy datapoint was spill- or af-confounded.

__global__ __launch_bounds__(256, 6) void scores_ctx(const float* __restrict__ enc,
                                                     const unsigned short* __restrict__ Uab,
                                                     const float* __restrict__ qb,
                                                     const float* __restrict__ Va,
                                                     const float* __restrict__ bva,
                                                     float* __restrict__ ctx_raw,
                                                     float* __restrict__ lsum) {
    __shared__ unsigned short elds[ROWS * ESTR];   // 14336 B
    __shared__ float s_qb[256];
    __shared__ float s_va[256];
    __shared__ float part[4][ROWS];
    __shared__ float wlds[ROWS];

    int bx  = blockIdx.x;
    int b   = bx >> 6;
    int t0  = (bx & 63) * ROWS;
    int tid = threadIdx.x, w = tid >> 6, lane = tid & 63, r = lane & 15, q = lane >> 4;

    // zero k-pad columns 200..223 (12 uints per row)
    for (int i = tid; i < ROWS * 12; i += 256) {
        int rr = i / 12, cc = i - rr * 12;
        *(unsigned*)(elds + rr * ESTR + 200 + 2 * cc) = 0u;
    }
    s_qb[tid] = (tid < H) ? qb[b * H + tid] : 0.f;
    s_va[tid] = (tid < H) ? Va[tid] : 0.f;
    float bv = bva[0];

    // stage enc[b, t0..t0+31, :] -> bf16 LDS, prefetch-by-1 (<=2 float4 live)
    const float4* src = (const float4*)(enc + (size_t)(b * T + t0) * H);
    float4 v = src[tid];
    for (int i = tid; i < ROWS * 50; i += 256) {
        float4 vn = v;
        int nxt = i + 256;
        if (nxt < ROWS * 50) vn = src[nxt];
        int rr = i / 50, cc = i - rr * 50;
        unsigned* dst = (unsigned*)(elds + rr * ESTR + cc * 4);
        dst[0] = pk2(v.x, v.y);
        dst[1] = pk2(v.z, v.w);
        v = vn;
    }
    __syncthreads();

    // scores: wave w owns m-tiles 4w..4w+3, processed as 2 groups of 2 (R0 form)
    float p[2] = {0.f, 0.f};
    for (int mig = 0; mig < 2; ++mig) {
        int m0 = w * 4 + mig * 2;
        short8 af[2][7];
        #pragma unroll
        for (int mi = 0; mi < 2; mi++)
            #pragma unroll
            for (int ks = 0; ks < 7; ks++)
                af[mi][ks] = *(const short8*)(Uab + ((m0 + mi) * 16 + r) * KP + ks * 32 + q * 8);

        #pragma unroll
        for (int nt = 0; nt < 2; nt++) {
            floatx4 C0 = (floatx4){0.f, 0.f, 0.f, 0.f};
            floatx4 C1 = (floatx4){0.f, 0.f, 0.f, 0.f};
            #pragma unroll
            for (int ks = 0; ks < 7; ks++) {
                short8 bf = *(const short8*)(elds + (nt * 16 + r) * ESTR + ks * 32 + q * 8);
                C0 = __builtin_amdgcn_mfma_f32_16x16x32_bf16(af[0][ks], bf, C0, 0, 0, 0);
                C1 = __builtin_amdgcn_mfma_f32_16x16x32_bf16(af[1][ks], bf, C1, 0, 0, 0);
            }
            float pp = 0.f;
            #pragma unroll
            for (int rg = 0; rg < 4; rg++) {
                int h0i = m0 * 16 + q * 4 + rg;
                int h1i = h0i + 16;
                pp += s_va[h0i] * ftanh(s_qb[h0i] + C0[rg]);
                pp += s_va[h1i] * ftanh(s_qb[h1i] + C1[rg]);
            }
            p[nt] += pp;
        }
    }
    #pragma unroll
    for (int nt = 0; nt < 2; nt++) {
        float pp = p[nt];
        pp += __shfl_xor(pp, 16);
        pp += __shfl_xor(pp, 32);
        if (q == 0) part[w][nt * 16 + r] = pp;
    }
    __syncthreads();

    if (w == 0) {   // wave 0: bound + softmax + lsum atomic
        float a = fabsf(s_va[lane]) + fabsf(s_va[lane + 64]) +
                  fabsf(s_va[lane + 128]) + fabsf(s_va[lane + 192]);
        #pragma unroll
        for (int d = 1; d < 64; d <<= 1) a += __shfl_xor(a, d);
        float bound = a + fabsf(bv);

        float we = 0.f;
        if (lane < ROWS) {
            float s = part[0][lane] + part[1][lane] + part[2][lane] + part[3][lane] + bv;
            we = __builtin_amdgcn_exp2f((s - bound) * 1.4426950408889634f);
            wlds[lane] = we;
        }
        #pragma unroll
        for (int d = 1; d < 64; d <<= 1) we += __shfl_xor(we, d);
        if (lane == 0) atomicAdd(&lsum[b], we);
    }
    __syncthreads();

    if (tid < H) {   // ctx[h] += sum_t w[t]*enc[t,h] from bf16 LDS
        float a0 = 0.f, a1 = 0.f, a2 = 0.f, a3 = 0.f;
        #pragma unroll
        for (int t = 0; t < ROWS; t += 4) {
            a0 = fmaf(wlds[t],     bf2f(elds[(t    ) * ESTR + tid]), a0);
            a1 = fmaf(wlds[t + 1], bf2f(elds[(t + 1) * ESTR + tid]), a1);
            a2 = fmaf(wlds[t + 2], bf2f(elds[(t + 2) * ESTR + tid]), a2);
            a3 = fmaf(wlds[t + 3], bf2f(elds[(t + 3) * ESTR + tid]), a3);
        }
        atomicAdd(&ctx_raw[b * H + tid], (a0 + a1) + (a2 + a3));
    }
}

// ---------------- decoder (fused gc prologue + 5 steps), 512 threads ----------------
__global__ __launch_bounds__(512) void decoder2(const float* __restrict__ x,
                                                const float* __restrict__ c0,
                                                const float* __restrict__ ctx_raw,
                                                const float* __restrict__ lsum,
                                                const float* __restrict__ h0,
                                                const float* __restrict__ WihT,
                                                const float* __restrict__ WhhT,
                                                const float* __restrict__ b_ih,
                                                const float* __restrict__ b_hh,
                                                const float* __restrict__ wx,
                                                const float* __restrict__ W1T,
                                                const float* __restrict__ b1,
                                                const float* __restrict__ W2T,
                                                const float* __restrict__ b2,
                                                const float* __restrict__ W3,
                                                const float* __restrict__ b3,
                                                float* __restrict__ out) {
    __shared__ float s_gc[G4];
    __shared__ float s_wx[G4];
    __shared__ float s_ctx[H];
    __shared__ float s_q[H];
    __shared__ float s_out[H];
    __shared__ float s_o1[100];
    __shared__ float s_o2[50];
    __shared__ float s_w3[64];
    __shared__ float s_x;
    int b = blockIdx.x, tid = threadIdx.x;

    if (tid < H) {
        float invl = 1.f / lsum[b];
        s_ctx[tid] = ctx_raw[b * H + tid] * invl;
        s_q[tid]   = h0[b * H + tid];
    }
    s_wx[tid] = wx[tid];
    if (tid < G4 - 512) s_wx[512 + tid] = wx[512 + tid];
    if (tid < 64) s_w3[tid] = (tid < 50) ? W3[tid] : 0.f;
    if (tid == 0) s_x = x[b];
    float b3v = b3[0];
    __syncthreads();

    // gc[j] = b_ih+b_hh + ctx.Wih[:,1:] + q.Whh   (two j per thread)
    {
        int j0 = tid;
        int j1 = 512 + ((tid < 288) ? tid : 287);
        float a0 = b_ih[j0] + b_hh[j0];
        float a1 = b_ih[j1] + b_hh[j1];
        #pragma unroll 4
        for (int k = 0; k < H; k++) {
            float cv = s_ctx[k], qv = s_q[k];
            a0 = fmaf(cv, WihT[k * G4 + j0], a0);
            a0 = fmaf(qv, WhhT[k * G4 + j0], a0);
            a1 = fmaf(cv, WihT[k * G4 + j1], a1);
            a1 = fmaf(qv, WhhT[k * G4 + j1], a1);
        }
        s_gc[j0] = a0;
        if (tid < 288) s_gc[512 + tid] = a1;
    }
    float cprev = (tid < H) ? c0[b * H + tid] : 0.f;
    __syncthreads();

    for (int s = 0; s < 5; s++) {
        float xv = s_x;
        if (tid < H) {
            float ig = s_gc[tid]         + xv * s_wx[tid];
            float fg = s_gc[H + tid]     + xv * s_wx[H + tid];
            float gg = s_gc[2 * H + tid] + xv * s_wx[2 * H + tid];
            float og = s_gc[3 * H + tid] + xv * s_wx[3 * H + tid];
            float c  = sigm(fg) * cprev + sigm(ig) * tanhf(gg);
            float hn = sigm(og) * tanhf(c);
            s_out[tid] = fmaxf(hn, 0.f);
        }
        __syncthreads();
        if (tid < 400) {   // W1: 4 lanes per output, k split 4x50
            int j = tid >> 2, q4 = tid & 3;
            float a = 0.f;
            const float* wp = W1T + (q4 * 50) * 100 + j;
            const float* op = s_out + q4 * 50;
            #pragma unroll 10
            for (int k = 0; k < 50; k++) a = fmaf(wp[k * 100], op[k], a);
            a += __shfl_xor(a, 1);
            a += __shfl_xor(a, 2);
            if (q4 == 0) s_o1[j] = fmaxf(a + b1[j], 0.f);
        }
        __syncthreads();
        if (tid < 200) {   // W2: 4 lanes per output, k split 4x25
            int j = tid >> 2, q4 = tid & 3;
            float a = 0.f;
            const float* wp = W2T + (q4 * 25) * 50 + j;
            const float* op = s_o1 + q4 * 25;
            #pragma unroll 5
            for (int k = 0; k < 25; k++) a = fmaf(wp[k * 50], op[k], a);
            a += __shfl_xor(a, 1);
            a += __shfl_xor(a, 2);
            if (q4 == 0) s_o2[j] = fmaxf(a + b2[j], 0.f);
        }
        __syncthreads();
        if (tid < 64) {   // W3: wave reduce
            float a = (tid < 50) ? s_w3[tid] * s_o2[tid] : 0.f;
            #pragma unroll
            for (int d = 1; d < 64; d <<= 1) a += __shfl_xor(a, d);
            if (tid == 0) {
                float y = a + b3v;
                out[b * 5 + s] = y;
                s_x = y;
            }
        }
        __syncthreads();
    }
}

// ---------------- launch ----------------
extern "C" void kernel_launch(void* const* d_in, const int* in_sizes, int n_in,
                              void* d_out, int out_size, void* d_ws, size_t ws_size,
                              hipStream_t stream) {
    (void)in_sizes; (void)n_in; (void)out_size; (void)ws_size;
    const float* x    = (const float*)d_in[0];
    const float* h0   = (const float*)d_in[1];
    const float* c0   = (const float*)d_in[2];
    const float* enc  = (const float*)d_in[3];
    const float* Wa   = (const float*)d_in[4];
    const float* ba   = (const float*)d_in[5];
    const float* Ua   = (const float*)d_in[6];
    const float* bua  = (const float*)d_in[7];
    const float* Va   = (const float*)d_in[8];
    const float* bva  = (const float*)d_in[9];
    const float* W_ih = (const float*)d_in[10];
    const float* W_hh = (const float*)d_in[11];
    const float* b_ih = (const float*)d_in[12];
    const float* b_hh = (const float*)d_in[13];
    const float* W1   = (const float*)d_in[14];
    const float* b1   = (const float*)d_in[15];
    const float* W2   = (const float*)d_in[16];
    const float* b2   = (const float*)d_in[17];
    const float* W3   = (const float*)d_in[18];
    const float* b3   = (const float*)d_in[19];
    float* out = (float*)d_out;

    char* ws = (char*)d_ws;
    unsigned short* Uab = (unsigned short*)(ws);   // 114688
    float* WihT    = (float*)(ws + 114688);        // 640000
    float* WhhT    = (float*)(ws + 754688);        // 640000
    float* wx      = (float*)(ws + 1394688);       // 3200
    float* qb      = (float*)(ws + 1397888);       // 102400
    float* W1T     = (float*)(ws + 1500288);       // 80000
    float* W2T     = (float*)(ws + 1580288);       // 20000
    float* ctx_raw = (float*)(ws + 1600288);       // 102400
    float* lsum    = (float*)(ws + 1702688);       // 512

    hipMemsetAsync(ws + 1600288, 0, 102912, stream);   // ctx_raw + lsum
    prep_all<<<dim3(1085), 256, 0, stream>>>(Ua, Wa, ba, bua, h0, W_ih, W_hh, W1, W2,
                                             Uab, WihT, WhhT, wx, qb, W1T, W2T);
    scores_ctx<<<dim3(8192), 256, 0, stream>>>(enc, Uab, qb, Va, bva, ctx_raw, lsum);
    decoder2<<<dim3(B), 512, 0, stream>>>(x, c0, ctx_raw, lsum, h0, WihT, WhhT,
                                          b_ih, b_hh, wx, W1T, b1, W2T, b2, W3, b3, out);
}

// Round 14
// 145.239 us; speedup vs baseline: 1.2043x; 1.2043x over previous
//
#include <hip/hip_runtime.h>
#include <math.h>

#define B 128
#define T 2048
#define H 200
#define G4 800    // 4*H
#define KP 224    // Uab row stride (bf16)
#define ESTR 224  // elds row stride (bf16) = KP (R0-proven)
#define ROWS 64   // t-rows per block

typedef short short8 __attribute__((ext_vector_type(8)));
typedef float floatx4 __attribute__((ext_vector_type(4)));

__device__ __forceinline__ unsigned short f2bf(float x) {
    unsigned u = __float_as_uint(x);
    return (unsigned short)((u + 0x7fffu + ((u >> 16) & 1u)) >> 16);
}
__device__ __forceinline__ float bf2f(unsigned short s) {
    return __uint_as_float(((unsigned)s) << 16);
}
// pack two floats -> two bf16 (round-nearest-away) in 3 VALU ops
__device__ __forceinline__ unsigned pk2(float a, float b) {
    return __builtin_amdgcn_perm(__float_as_uint(b) + 0x8000u,
                                 __float_as_uint(a) + 0x8000u, 0x07060302u);
}
// tanh(x) = 1 - 2/(exp(2x)+1), hw exp2 + rcp (~1e-6 rel err)
__device__ __forceinline__ float ftanh(float x) {
    float e = __builtin_amdgcn_exp2f(x * 2.885390081777927f);
    float r = __builtin_amdgcn_rcpf(e + 1.f);
    return fmaf(-2.f, r, 1.f);
}
__device__ __forceinline__ float sigm(float x) { return 1.f / (1.f + expf(-x)); }

// ---------------- prep_all ----------------
// blocks 0..255    : Uab row (bf16, zero-padded [256][224])
// blocks 256..455  : W_ihT[k][j] = W_ih[j][1+k]
// blocks 456..655  : W_hhT[k][j] = W_hh[j][k]
// block  656       : wx[j] = W_ih[j][0]
// blocks 657..784  : qb[b][h] = h0[b] @ Wa.T + ba + bua   (float4 dot)
// blocks 785..984  : W1T[k][j] = W1[j][k]   (k<200, j<100)
// blocks 985..1084 : W2T[k][j] = W2[j][k]   (k<100, j<50)
__global__ __launch_bounds__(256) void prep_all(const float* __restrict__ Ua,
                                                const float* __restrict__ Wa,
                                                const float* __restrict__ ba,
                                                const float* __restrict__ bua,
                                                const float* __restrict__ h0,
                                                const float* __restrict__ W_ih,
                                                const float* __restrict__ W_hh,
                                                const float* __restrict__ W1,
                                                const float* __restrict__ W2,
                                                unsigned short* __restrict__ Uab,
                                                float* __restrict__ WihT,
                                                float* __restrict__ WhhT,
                                                float* __restrict__ wx,
                                                float* __restrict__ qb,
                                                float* __restrict__ W1T,
                                                float* __restrict__ W2T) {
    __shared__ __align__(16) float qs[H];
    int bx = blockIdx.x, tid = threadIdx.x;
    if (bx < 256) {
        if (tid < KP) {
            float v = (bx < H && tid < H) ? Ua[bx * H + tid] : 0.f;
            Uab[bx * KP + tid] = f2bf(v);
        }
    } else if (bx < 456) {
        int k = bx - 256;
        for (int j = tid; j < G4; j += 256) WihT[k * G4 + j] = W_ih[(size_t)j * (H + 1) + 1 + k];
    } else if (bx < 656) {
        int k = bx - 456;
        for (int j = tid; j < G4; j += 256) WhhT[k * G4 + j] = W_hh[(size_t)j * H + k];
    } else if (bx == 656) {
        for (int j = tid; j < G4; j += 256) wx[j] = W_ih[(size_t)j * (H + 1)];
    } else if (bx < 785) {
        int b = bx - 657;
        if (tid < H) qs[tid] = h0[b * H + tid];
        __syncthreads();
        if (tid < H) {
            float a = ba[tid] + bua[tid];
            const float4* w  = (const float4*)(Wa + tid * H);
            const float4* qv = (const float4*)qs;
            #pragma unroll 8
            for (int k = 0; k < 50; k++) {
                float4 wv = w[k], q4 = qv[k];
                a = fmaf(wv.x, q4.x, a);
                a = fmaf(wv.y, q4.y, a);
                a = fmaf(wv.z, q4.z, a);
                a = fmaf(wv.w, q4.w, a);
            }
            qb[b * H + tid] = a;
        }
    } else if (bx < 985) {
        int k = bx - 785;
        if (tid < 100) W1T[k * 100 + tid] = W1[tid * H + k];
    } else {
        int k = bx - 985;
        if (tid < 50) W2T[k * 50 + tid] = W2[tid * 100 + k];
    }
}

// ---------------- scores + bounded-softmax + context (R0 form + staged prefetch) ----------------
// Session-best form (R12, 146.0 us total / ~135.5 us scores). R0's exact scores
// structure -- the ONLY form measured spill-free at 64 VGPR across 14 rounds:
// rolled 2-iteration mig loop, af[2][7] reloaded per group from L2-hot Uab,
// 16 m-tiles (h up to 255; s_va/s_qb zero-padded to 256 annihilate h>=200),
// prefetch-by-1 loop staging (<=2 float4 live). Measured invariants: VGPR 64,
// LDS 32,256 B, occ ~43%, WRITE ~3.3 MB (no spill), dur invariant to L3-residency
// -> latency/issue plateau; occupancy 43-81% and all pipelining variants regress.

__global__ __launch_bounds__(256, 4) void scores_ctx(const float* __restrict__ enc,
                                                     const unsigned short* __restrict__ Uab,
                                                     const float* __restrict__ qb,
                                                     const float* __restrict__ Va,
                                                     const float* __restrict__ bva,
                                                     float* __restrict__ ctx_raw,
                                                     float* __restrict__ lsum) {
    __shared__ unsigned short elds[ROWS * ESTR];   // 28672 B
    __shared__ float s_qb[256];
    __shared__ float s_va[256];
    __shared__ float part[4][ROWS];
    __shared__ float wlds[ROWS];

    int bx  = blockIdx.x;
    int b   = bx >> 5;
    int t0  = (bx & 31) * ROWS;
    int tid = threadIdx.x, w = tid >> 6, lane = tid & 63, r = lane & 15, q = lane >> 4;

    // zero k-pad columns 200..223 (12 uints per row)
    for (int i = tid; i < ROWS * 12; i += 256) {
        int rr = i / 12, cc = i - rr * 12;
        *(unsigned*)(elds + rr * ESTR + 200 + 2 * cc) = 0u;
    }
    s_qb[tid] = (tid < H) ? qb[b * H + tid] : 0.f;
    s_va[tid] = (tid < H) ? Va[tid] : 0.f;
    float bv = bva[0];

    // stage enc[b, t0..t0+63, :] -> bf16 LDS, prefetch-by-1 (<=2 float4 live)
    const float4* src = (const float4*)(enc + (size_t)(b * T + t0) * H);
    float4 v = src[tid];
    for (int i = tid; i < ROWS * 50; i += 256) {
        float4 vn = v;
        int nxt = i + 256;
        if (nxt < ROWS * 50) vn = src[nxt];
        int rr = i / 50, cc = i - rr * 50;
        unsigned* dst = (unsigned*)(elds + rr * ESTR + cc * 4);
        dst[0] = pk2(v.x, v.y);
        dst[1] = pk2(v.z, v.w);
        v = vn;
    }
    __syncthreads();

    // scores: wave w owns m-tiles 4w..4w+3, processed as 2 groups of 2 (R0 form)
    float p[4] = {0.f, 0.f, 0.f, 0.f};
    for (int mig = 0; mig < 2; ++mig) {
        int m0 = w * 4 + mig * 2;
        short8 af[2][7];
        #pragma unroll
        for (int mi = 0; mi < 2; mi++)
            #pragma unroll
            for (int ks = 0; ks < 7; ks++)
                af[mi][ks] = *(const short8*)(Uab + ((m0 + mi) * 16 + r) * KP + ks * 32 + q * 8);

        #pragma unroll
        for (int nt = 0; nt < 4; nt++) {
            floatx4 C0 = (floatx4){0.f, 0.f, 0.f, 0.f};
            floatx4 C1 = (floatx4){0.f, 0.f, 0.f, 0.f};
            #pragma unroll
            for (int ks = 0; ks < 7; ks++) {
                short8 bf = *(const short8*)(elds + (nt * 16 + r) * ESTR + ks * 32 + q * 8);
                C0 = __builtin_amdgcn_mfma_f32_16x16x32_bf16(af[0][ks], bf, C0, 0, 0, 0);
                C1 = __builtin_amdgcn_mfma_f32_16x16x32_bf16(af[1][ks], bf, C1, 0, 0, 0);
            }
            float pp = 0.f;
            #pragma unroll
            for (int rg = 0; rg < 4; rg++) {
                int h0i = m0 * 16 + q * 4 + rg;
                int h1i = h0i + 16;
                pp += s_va[h0i] * ftanh(s_qb[h0i] + C0[rg]);
                pp += s_va[h1i] * ftanh(s_qb[h1i] + C1[rg]);
            }
            p[nt] += pp;
        }
    }
    #pragma unroll
    for (int nt = 0; nt < 4; nt++) {
        float pp = p[nt];
        pp += __shfl_xor(pp, 16);
        pp += __shfl_xor(pp, 32);
        if (q == 0) part[w][nt * 16 + r] = pp;
    }
    __syncthreads();

    if (w == 0) {   // wave 0: bound + softmax + lsum atomic
        float a = fabsf(s_va[lane]) + fabsf(s_va[lane + 64]) +
                  fabsf(s_va[lane + 128]) + fabsf(s_va[lane + 192]);
        #pragma unroll
        for (int d = 1; d < 64; d <<= 1) a += __shfl_xor(a, d);
        float bound = a + fabsf(bv);

        float s  = part[0][lane] + part[1][lane] + part[2][lane] + part[3][lane] + bv;
        float we = __builtin_amdgcn_exp2f((s - bound) * 1.4426950408889634f);
        wlds[lane] = we;
        #pragma unroll
        for (int d = 1; d < 64; d <<= 1) we += __shfl_xor(we, d);
        if (lane == 0) atomicAdd(&lsum[b], we);
    }
    __syncthreads();

    if (tid < H) {   // ctx[h] += sum_t w[t]*enc[t,h] from bf16 LDS
        float a0 = 0.f, a1 = 0.f, a2 = 0.f, a3 = 0.f;
        #pragma unroll 4
        for (int t = 0; t < ROWS; t += 4) {
            a0 = fmaf(wlds[t],     bf2f(elds[(t    ) * ESTR + tid]), a0);
            a1 = fmaf(wlds[t + 1], bf2f(elds[(t + 1) * ESTR + tid]), a1);
            a2 = fmaf(wlds[t + 2], bf2f(elds[(t + 2) * ESTR + tid]), a2);
            a3 = fmaf(wlds[t + 3], bf2f(elds[(t + 3) * ESTR + tid]), a3);
        }
        atomicAdd(&ctx_raw[b * H + tid], (a0 + a1) + (a2 + a3));
    }
}

// ---------------- decoder (fused gc prologue + 5 steps), 512 threads ----------------
__global__ __launch_bounds__(512) void decoder2(const float* __restrict__ x,
                                                const float* __restrict__ c0,
                                                const float* __restrict__ ctx_raw,
                                                const float* __restrict__ lsum,
                                                const float* __restrict__ h0,
                                                const float* __restrict__ WihT,
                                                const float* __restrict__ WhhT,
                                                const float* __restrict__ b_ih,
                                                const float* __restrict__ b_hh,
                                                const float* __restrict__ wx,
                                                const float* __restrict__ W1T,
                                                const float* __restrict__ b1,
                                                const float* __restrict__ W2T,
                                                const float* __restrict__ b2,
                                                const float* __restrict__ W3,
                                                const float* __restrict__ b3,
                                                float* __restrict__ out) {
    __shared__ float s_gc[G4];
    __shared__ float s_wx[G4];
    __shared__ float s_ctx[H];
    __shared__ float s_q[H];
    __shared__ float s_out[H];
    __shared__ float s_o1[100];
    __shared__ float s_o2[50];
    __shared__ float s_w3[64];
    __shared__ float s_x;
    int b = blockIdx.x, tid = threadIdx.x;

    if (tid < H) {
        float invl = 1.f / lsum[b];
        s_ctx[tid] = ctx_raw[b * H + tid] * invl;
        s_q[tid]   = h0[b * H + tid];
    }
    s_wx[tid] = wx[tid];
    if (tid < G4 - 512) s_wx[512 + tid] = wx[512 + tid];
    if (tid < 64) s_w3[tid] = (tid < 50) ? W3[tid] : 0.f;
    if (tid == 0) s_x = x[b];
    float b3v = b3[0];
    __syncthreads();

    // gc[j] = b_ih+b_hh + ctx.Wih[:,1:] + q.Whh   (two j per thread)
    {
        int j0 = tid;
        int j1 = 512 + ((tid < 288) ? tid : 287);
        float a0 = b_ih[j0] + b_hh[j0];
        float a1 = b_ih[j1] + b_hh[j1];
        #pragma unroll 4
        for (int k = 0; k < H; k++) {
            float cv = s_ctx[k], qv = s_q[k];
            a0 = fmaf(cv, WihT[k * G4 + j0], a0);
            a0 = fmaf(qv, WhhT[k * G4 + j0], a0);
            a1 = fmaf(cv, WihT[k * G4 + j1], a1);
            a1 = fmaf(qv, WhhT[k * G4 + j1], a1);
        }
        s_gc[j0] = a0;
        if (tid < 288) s_gc[512 + tid] = a1;
    }
    float cprev = (tid < H) ? c0[b * H + tid] : 0.f;
    __syncthreads();

    for (int s = 0; s < 5; s++) {
        float xv = s_x;
        if (tid < H) {
            float ig = s_gc[tid]         + xv * s_wx[tid];
            float fg = s_gc[H + tid]     + xv * s_wx[H + tid];
            float gg = s_gc[2 * H + tid] + xv * s_wx[2 * H + tid];
            float og = s_gc[3 * H + tid] + xv * s_wx[3 * H + tid];
            float c  = sigm(fg) * cprev + sigm(ig) * tanhf(gg);
            float hn = sigm(og) * tanhf(c);
            s_out[tid] = fmaxf(hn, 0.f);
        }
        __syncthreads();
        if (tid < 400) {   // W1: 4 lanes per output, k split 4x50
            int j = tid >> 2, q4 = tid & 3;
            float a = 0.f;
            const float* wp = W1T + (q4 * 50) * 100 + j;
            const float* op = s_out + q4 * 50;
            #pragma unroll 10
            for (int k = 0; k < 50; k++) a = fmaf(wp[k * 100], op[k], a);
            a += __shfl_xor(a, 1);
            a += __shfl_xor(a, 2);
            if (q4 == 0) s_o1[j] = fmaxf(a + b1[j], 0.f);
        }
        __syncthreads();
        if (tid < 200) {   // W2: 4 lanes per output, k split 4x25
            int j = tid >> 2, q4 = tid & 3;
            float a = 0.f;
            const float* wp = W2T + (q4 * 25) * 50 + j;
            const float* op = s_o1 + q4 * 25;
            #pragma unroll 5
            for (int k = 0; k < 25; k++) a = fmaf(wp[k * 50], op[k], a);
            a += __shfl_xor(a, 1);
            a += __shfl_xor(a, 2);
            if (q4 == 0) s_o2[j] = fmaxf(a + b2[j], 0.f);
        }
        __syncthreads();
        if (tid < 64) {   // W3: wave reduce
            float a = (tid < 50) ? s_w3[tid] * s_o2[tid] : 0.f;
            #pragma unroll
            for (int d = 1; d < 64; d <<= 1) a += __shfl_xor(a, d);
            if (tid == 0) {
                float y = a + b3v;
                out[b * 5 + s] = y;
                s_x = y;
            }
        }
        __syncthreads();
    }
}

// ---------------- launch ----------------
extern "C" void kernel_launch(void* const* d_in, const int* in_sizes, int n_in,
                              void* d_out, int out_size, void* d_ws, size_t ws_size,
                              hipStream_t stream) {
    (void)in_sizes; (void)n_in; (void)out_size; (void)ws_size;
    const float* x    = (const float*)d_in[0];
    const float* h0   = (const float*)d_in[1];
    const float* c0   = (const float*)d_in[2];
    const float* enc  = (const float*)d_in[3];
    const float* Wa   = (const float*)d_in[4];
    const float* ba   = (const float*)d_in[5];
    const float* Ua   = (const float*)d_in[6];
    const float* bua  = (const float*)d_in[7];
    const float* Va   = (const float*)d_in[8];
    const float* bva  = (const float*)d_in[9];
    const float* W_ih = (const float*)d_in[10];
    const float* W_hh = (const float*)d_in[11];
    const float* b_ih = (const float*)d_in[12];
    const float* b_hh = (const float*)d_in[13];
    const float* W1   = (const float*)d_in[14];
    const float* b1   = (const float*)d_in[15];
    const float* W2   = (const float*)d_in[16];
    const float* b2   = (const float*)d_in[17];
    const float* W3   = (const float*)d_in[18];
    const float* b3   = (const float*)d_in[19];
    float* out = (float*)d_out;

    char* ws = (char*)d_ws;
    unsigned short* Uab = (unsigned short*)(ws);   // 114688
    float* WihT    = (float*)(ws + 114688);        // 640000
    float* WhhT    = (float*)(ws + 754688);        // 640000
    float* wx      = (float*)(ws + 1394688);       // 3200
    float* qb      = (float*)(ws + 1397888);       // 102400
    float* W1T     = (float*)(ws + 1500288);       // 80000
    float* W2T     = (float*)(ws + 1580288);       // 20000
    float* ctx_raw = (float*)(ws + 1600288);       // 102400
    float* lsum    = (float*)(ws + 1702688);       // 512

    hipMemsetAsync(ws + 1600288, 0, 102912, stream);   // ctx_raw + lsum
    prep_all<<<dim3(1085), 256, 0, stream>>>(Ua, Wa, ba, bua, h0, W_ih, W_hh, W1, W2,
                                             Uab, WihT, WhhT, wx, qb, W1T, W2T);
    scores_ctx<<<dim3(4096), 256, 0, stream>>>(enc, Uab, qb, Va, bva, ctx_raw, lsum);
    decoder2<<<dim3(B), 512, 0, stream>>>(x, c0, ctx_raw, lsum, h0, WihT, WhhT,
                                          b_ih, b_hh, wx, W1T, b1, W2T, b2, W3, b3, out);
}

// Round 15
// 140.200 us; speedup vs baseline: 1.2476x; 1.0359x over previous
//
#include <hip/hip_runtime.h>
#include <math.h>

#define B 128
#define T 2048
#define H 200
#define G4 800    // 4*H
#define KP 224    // Uab row stride (bf16)
#define ESTR 224  // elds row stride (bf16) = KP (R0-proven)
#define ROWS 64   // t-rows per block

typedef short short8 __attribute__((ext_vector_type(8)));
typedef float floatx4 __attribute__((ext_vector_type(4)));

__device__ __forceinline__ unsigned short f2bf(float x) {
    unsigned u = __float_as_uint(x);
    return (unsigned short)((u + 0x7fffu + ((u >> 16) & 1u)) >> 16);
}
__device__ __forceinline__ float bf2f(unsigned short s) {
    return __uint_as_float(((unsigned)s) << 16);
}
// pack two floats -> two bf16 (round-nearest-away) in 3 VALU ops
__device__ __forceinline__ unsigned pk2(float a, float b) {
    return __builtin_amdgcn_perm(__float_as_uint(b) + 0x8000u,
                                 __float_as_uint(a) + 0x8000u, 0x07060302u);
}
// tanh(x) = 1 - 2/(exp(2x)+1), hw exp2 + rcp (~1e-6 rel err)
__device__ __forceinline__ float ftanh(float x) {
    float e = __builtin_amdgcn_exp2f(x * 2.885390081777927f);
    float r = __builtin_amdgcn_rcpf(e + 1.f);
    return fmaf(-2.f, r, 1.f);
}
__device__ __forceinline__ float sigm(float x) { return 1.f / (1.f + expf(-x)); }

// ---------------- prep_all ----------------
// blocks 0..255    : Uab row (bf16, zero-padded [256][224])
// blocks 256..455  : W_ihT[k][j] = W_ih[j][1+k]
// blocks 456..655  : W_hhT[k][j] = W_hh[j][k]
// block  656       : wx[j] = W_ih[j][0]
// blocks 657..784  : qb[b][h] = h0[b] @ Wa.T + ba + bua   (float4 dot)
// blocks 785..984  : W1T[k][j] = W1[j][k]   (k<200, j<100)
// blocks 985..1084 : W2T[k][j] = W2[j][k]   (k<100, j<50)
// blocks 1085..1184: ctx_raw zero (replaces the standalone hipMemsetAsync node)
// block  1185      : lsum zero
__global__ __launch_bounds__(256) void prep_all(const float* __restrict__ Ua,
                                                const float* __restrict__ Wa,
                                                const float* __restrict__ ba,
                                                const float* __restrict__ bua,
                                                const float* __restrict__ h0,
                                                const float* __restrict__ W_ih,
                                                const float* __restrict__ W_hh,
                                                const float* __restrict__ W1,
                                                const float* __restrict__ W2,
                                                unsigned short* __restrict__ Uab,
                                                float* __restrict__ WihT,
                                                float* __restrict__ WhhT,
                                                float* __restrict__ wx,
                                                float* __restrict__ qb,
                                                float* __restrict__ W1T,
                                                float* __restrict__ W2T,
                                                float* __restrict__ ctx_raw,
                                                float* __restrict__ lsum) {
    __shared__ __align__(16) float qs[H];
    int bx = blockIdx.x, tid = threadIdx.x;
    if (bx < 256) {
        if (tid < KP) {
            float v = (bx < H && tid < H) ? Ua[bx * H + tid] : 0.f;
            Uab[bx * KP + tid] = f2bf(v);
        }
    } else if (bx < 456) {
        int k = bx - 256;
        for (int j = tid; j < G4; j += 256) WihT[k * G4 + j] = W_ih[(size_t)j * (H + 1) + 1 + k];
    } else if (bx < 656) {
        int k = bx - 456;
        for (int j = tid; j < G4; j += 256) WhhT[k * G4 + j] = W_hh[(size_t)j * H + k];
    } else if (bx == 656) {
        for (int j = tid; j < G4; j += 256) wx[j] = W_ih[(size_t)j * (H + 1)];
    } else if (bx < 785) {
        int b = bx - 657;
        if (tid < H) qs[tid] = h0[b * H + tid];
        __syncthreads();
        if (tid < H) {
            float a = ba[tid] + bua[tid];
            const float4* w  = (const float4*)(Wa + tid * H);
            const float4* qv = (const float4*)qs;
            #pragma unroll 8
            for (int k = 0; k < 50; k++) {
                float4 wv = w[k], q4 = qv[k];
                a = fmaf(wv.x, q4.x, a);
                a = fmaf(wv.y, q4.y, a);
                a = fmaf(wv.z, q4.z, a);
                a = fmaf(wv.w, q4.w, a);
            }
            qb[b * H + tid] = a;
        }
    } else if (bx < 985) {
        int k = bx - 785;
        if (tid < 100) W1T[k * 100 + tid] = W1[tid * H + k];
    } else if (bx < 1085) {
        int k = bx - 985;
        if (tid < 50) W2T[k * 50 + tid] = W2[tid * 100 + k];
    } else if (bx < 1185) {
        ctx_raw[(bx - 1085) * 256 + tid] = 0.f;   // 100*256 = 25600 = B*H exactly
    } else {
        if (tid < B) lsum[tid] = 0.f;
    }
}

// ---------------- scores + bounded-softmax + context (R0 form + staged prefetch) ----------------
// Session-best form (R12/R14, 145.2 us total / ~135 us scores). R0's exact scores
// structure -- the ONLY form measured spill-free at 64 VGPR across 15 rounds:
// rolled 2-iteration mig loop, af[2][7] reloaded per group from L2-hot Uab,
// 16 m-tiles (h up to 255; s_va/s_qb zero-padded to 256 annihilate h>=200),
// prefetch-by-1 loop staging (<=2 float4 live). Measured invariants: VGPR 64,
// LDS 32,256 B, occ ~44%, WRITE ~3.3 MB (no spill), dur invariant to L3-residency
// -> latency/issue plateau; occupancy 43-81% and all pipelining variants regress.
// DO NOT perturb: launch bounds, the rolled mig loop, or the staging form --
// every variant (R1,R7-R11,R13) flipped the allocator into spill or af-sinking.

__global__ __launch_bounds__(256, 4) void scores_ctx(const float* __restrict__ enc,
                                                     const unsigned short* __restrict__ Uab,
                                                     const float* __restrict__ qb,
                                                     const float* __restrict__ Va,
                                                     const float* __restrict__ bva,
                                                     float* __restrict__ ctx_raw,
                                                     float* __restrict__ lsum) {
    __shared__ unsigned short elds[ROWS * ESTR];   // 28672 B
    __shared__ float s_qb[256];
    __shared__ float s_va[256];
    __shared__ float part[4][ROWS];
    __shared__ float wlds[ROWS];

    int bx  = blockIdx.x;
    int b   = bx >> 5;
    int t0  = (bx & 31) * ROWS;
    int tid = threadIdx.x, w = tid >> 6, lane = tid & 63, r = lane & 15, q = lane >> 4;

    // zero k-pad columns 200..223 (12 uints per row)
    for (int i = tid; i < ROWS * 12; i += 256) {
        int rr = i / 12, cc = i - rr * 12;
        *(unsigned*)(elds + rr * ESTR + 200 + 2 * cc) = 0u;
    }
    s_qb[tid] = (tid < H) ? qb[b * H + tid] : 0.f;
    s_va[tid] = (tid < H) ? Va[tid] : 0.f;
    float bv = bva[0];

    // stage enc[b, t0..t0+63, :] -> bf16 LDS, prefetch-by-1 (<=2 float4 live)
    const float4* src = (const float4*)(enc + (size_t)(b * T + t0) * H);
    float4 v = src[tid];
    for (int i = tid; i < ROWS * 50; i += 256) {
        float4 vn = v;
        int nxt = i + 256;
        if (nxt < ROWS * 50) vn = src[nxt];
        int rr = i / 50, cc = i - rr * 50;
        unsigned* dst = (unsigned*)(elds + rr * ESTR + cc * 4);
        dst[0] = pk2(v.x, v.y);
        dst[1] = pk2(v.z, v.w);
        v = vn;
    }
    __syncthreads();

    // scores: wave w owns m-tiles 4w..4w+3, processed as 2 groups of 2 (R0 form)
    float p[4] = {0.f, 0.f, 0.f, 0.f};
    for (int mig = 0; mig < 2; ++mig) {
        int m0 = w * 4 + mig * 2;
        short8 af[2][7];
        #pragma unroll
        for (int mi = 0; mi < 2; mi++)
            #pragma unroll
            for (int ks = 0; ks < 7; ks++)
                af[mi][ks] = *(const short8*)(Uab + ((m0 + mi) * 16 + r) * KP + ks * 32 + q * 8);

        #pragma unroll
        for (int nt = 0; nt < 4; nt++) {
            floatx4 C0 = (floatx4){0.f, 0.f, 0.f, 0.f};
            floatx4 C1 = (floatx4){0.f, 0.f, 0.f, 0.f};
            #pragma unroll
            for (int ks = 0; ks < 7; ks++) {
                short8 bf = *(const short8*)(elds + (nt * 16 + r) * ESTR + ks * 32 + q * 8);
                C0 = __builtin_amdgcn_mfma_f32_16x16x32_bf16(af[0][ks], bf, C0, 0, 0, 0);
                C1 = __builtin_amdgcn_mfma_f32_16x16x32_bf16(af[1][ks], bf, C1, 0, 0, 0);
            }
            float pp = 0.f;
            #pragma unroll
            for (int rg = 0; rg < 4; rg++) {
                int h0i = m0 * 16 + q * 4 + rg;
                int h1i = h0i + 16;
                pp += s_va[h0i] * ftanh(s_qb[h0i] + C0[rg]);
                pp += s_va[h1i] * ftanh(s_qb[h1i] + C1[rg]);
            }
            p[nt] += pp;
        }
    }
    #pragma unroll
    for (int nt = 0; nt < 4; nt++) {
        float pp = p[nt];
        pp += __shfl_xor(pp, 16);
        pp += __shfl_xor(pp, 32);
        if (q == 0) part[w][nt * 16 + r] = pp;
    }
    __syncthreads();

    if (w == 0) {   // wave 0: bound + softmax + lsum atomic
        float a = fabsf(s_va[lane]) + fabsf(s_va[lane + 64]) +
                  fabsf(s_va[lane + 128]) + fabsf(s_va[lane + 192]);
        #pragma unroll
        for (int d = 1; d < 64; d <<= 1) a += __shfl_xor(a, d);
        float bound = a + fabsf(bv);

        float s  = part[0][lane] + part[1][lane] + part[2][lane] + part[3][lane] + bv;
        float we = __builtin_amdgcn_exp2f((s - bound) * 1.4426950408889634f);
        wlds[lane] = we;
        #pragma unroll
        for (int d = 1; d < 64; d <<= 1) we += __shfl_xor(we, d);
        if (lane == 0) atomicAdd(&lsum[b], we);
    }
    __syncthreads();

    if (tid < H) {   // ctx[h] += sum_t w[t]*enc[t,h] from bf16 LDS
        float a0 = 0.f, a1 = 0.f, a2 = 0.f, a3 = 0.f;
        #pragma unroll 4
        for (int t = 0; t < ROWS; t += 4) {
            a0 = fmaf(wlds[t],     bf2f(elds[(t    ) * ESTR + tid]), a0);
            a1 = fmaf(wlds[t + 1], bf2f(elds[(t + 1) * ESTR + tid]), a1);
            a2 = fmaf(wlds[t + 2], bf2f(elds[(t + 2) * ESTR + tid]), a2);
            a3 = fmaf(wlds[t + 3], bf2f(elds[(t + 3) * ESTR + tid]), a3);
        }
        atomicAdd(&ctx_raw[b * H + tid], (a0 + a1) + (a2 + a3));
    }
}

// ---------------- decoder (fused gc prologue + 5 steps), 512 threads ----------------
__global__ __launch_bounds__(512) void decoder2(const float* __restrict__ x,
                                                const float* __restrict__ c0,
                                                const float* __restrict__ ctx_raw,
                                                const float* __restrict__ lsum,
                                                const float* __restrict__ h0,
                                                const float* __restrict__ WihT,
                                                const float* __restrict__ WhhT,
                                                const float* __restrict__ b_ih,
                                                const float* __restrict__ b_hh,
                                                const float* __restrict__ wx,
                                                const float* __restrict__ W1T,
                                                const float* __restrict__ b1,
                                                const float* __restrict__ W2T,
                                                const float* __restrict__ b2,
                                                const float* __restrict__ W3,
                                                const float* __restrict__ b3,
                                                float* __restrict__ out) {
    __shared__ float s_gc[G4];
    __shared__ float s_wx[G4];
    __shared__ float s_ctx[H];
    __shared__ float s_q[H];
    __shared__ float s_out[H];
    __shared__ float s_o1[100];
    __shared__ float s_o2[50];
    __shared__ float s_w3[64];
    __shared__ float s_x;
    int b = blockIdx.x, tid = threadIdx.x;

    if (tid < H) {
        float invl = 1.f / lsum[b];
        s_ctx[tid] = ctx_raw[b * H + tid] * invl;
        s_q[tid]   = h0[b * H + tid];
    }
    s_wx[tid] = wx[tid];
    if (tid < G4 - 512) s_wx[512 + tid] = wx[512 + tid];
    if (tid < 64) s_w3[tid] = (tid < 50) ? W3[tid] : 0.f;
    if (tid == 0) s_x = x[b];
    float b3v = b3[0];
    __syncthreads();

    // gc[j] = b_ih+b_hh + ctx.Wih[:,1:] + q.Whh   (two j per thread)
    {
        int j0 = tid;
        int j1 = 512 + ((tid < 288) ? tid : 287);
        float a0 = b_ih[j0] + b_hh[j0];
        float a1 = b_ih[j1] + b_hh[j1];
        #pragma unroll 4
        for (int k = 0; k < H; k++) {
            float cv = s_ctx[k], qv = s_q[k];
            a0 = fmaf(cv, WihT[k * G4 + j0], a0);
            a0 = fmaf(qv, WhhT[k * G4 + j0], a0);
            a1 = fmaf(cv, WihT[k * G4 + j1], a1);
            a1 = fmaf(qv, WhhT[k * G4 + j1], a1);
        }
        s_gc[j0] = a0;
        if (tid < 288) s_gc[512 + tid] = a1;
    }
    float cprev = (tid < H) ? c0[b * H + tid] : 0.f;
    __syncthreads();

    for (int s = 0; s < 5; s++) {
        float xv = s_x;
        if (tid < H) {
            float ig = s_gc[tid]         + xv * s_wx[tid];
            float fg = s_gc[H + tid]     + xv * s_wx[H + tid];
            float gg = s_gc[2 * H + tid] + xv * s_wx[2 * H + tid];
            float og = s_gc[3 * H + tid] + xv * s_wx[3 * H + tid];
            float c  = sigm(fg) * cprev + sigm(ig) * tanhf(gg);
            float hn = sigm(og) * tanhf(c);
            s_out[tid] = fmaxf(hn, 0.f);
        }
        __syncthreads();
        if (tid < 400) {   // W1: 4 lanes per output, k split 4x50
            int j = tid >> 2, q4 = tid & 3;
            float a = 0.f;
            const float* wp = W1T + (q4 * 50) * 100 + j;
            const float* op = s_out + q4 * 50;
            #pragma unroll 10
            for (int k = 0; k < 50; k++) a = fmaf(wp[k * 100], op[k], a);
            a += __shfl_xor(a, 1);
            a += __shfl_xor(a, 2);
            if (q4 == 0) s_o1[j] = fmaxf(a + b1[j], 0.f);
        }
        __syncthreads();
        if (tid < 200) {   // W2: 4 lanes per output, k split 4x25
            int j = tid >> 2, q4 = tid & 3;
            float a = 0.f;
            const float* wp = W2T + (q4 * 25) * 50 + j;
            const float* op = s_o1 + q4 * 25;
            #pragma unroll 5
            for (int k = 0; k < 25; k++) a = fmaf(wp[k * 50], op[k], a);
            a += __shfl_xor(a, 1);
            a += __shfl_xor(a, 2);
            if (q4 == 0) s_o2[j] = fmaxf(a + b2[j], 0.f);
        }
        __syncthreads();
        if (tid < 64) {   // W3: wave reduce
            float a = (tid < 50) ? s_w3[tid] * s_o2[tid] : 0.f;
            #pragma unroll
            for (int d = 1; d < 64; d <<= 1) a += __shfl_xor(a, d);
            if (tid == 0) {
                float y = a + b3v;
                out[b * 5 + s] = y;
                s_x = y;
            }
        }
        __syncthreads();
    }
}

// ---------------- launch ----------------
extern "C" void kernel_launch(void* const* d_in, const int* in_sizes, int n_in,
                              void* d_out, int out_size, void* d_ws, size_t ws_size,
                              hipStream_t stream) {
    (void)in_sizes; (void)n_in; (void)out_size; (void)ws_size;
    const float* x    = (const float*)d_in[0];
    const float* h0   = (const float*)d_in[1];
    const float* c0   = (const float*)d_in[2];
    const float* enc  = (const float*)d_in[3];
    const float* Wa   = (const float*)d_in[4];
    const float* ba   = (const float*)d_in[5];
    const float* Ua   = (const float*)d_in[6];
    const float* bua  = (const float*)d_in[7];
    const float* Va   = (const float*)d_in[8];
    const float* bva  = (const float*)d_in[9];
    const float* W_ih = (const float*)d_in[10];
    const float* W_hh = (const float*)d_in[11];
    const float* b_ih = (const float*)d_in[12];
    const float* b_hh = (const float*)d_in[13];
    const float* W1   = (const float*)d_in[14];
    const float* b1   = (const float*)d_in[15];
    const float* W2   = (const float*)d_in[16];
    const float* b2   = (const float*)d_in[17];
    const float* W3   = (const float*)d_in[18];
    const float* b3   = (const float*)d_in[19];
    float* out = (float*)d_out;

    char* ws = (char*)d_ws;
    unsigned short* Uab = (unsigned short*)(ws);   // 114688
    float* WihT    = (float*)(ws + 114688);        // 640000
    float* WhhT    = (float*)(ws + 754688);        // 640000
    float* wx      = (float*)(ws + 1394688);       // 3200
    float* qb      = (float*)(ws + 1397888);       // 102400
    float* W1T     = (float*)(ws + 1500288);       // 80000
    float* W2T     = (float*)(ws + 1580288);       // 20000
    float* ctx_raw = (float*)(ws + 1600288);       // 102400
    float* lsum    = (float*)(ws + 1702688);       // 512

    prep_all<<<dim3(1186), 256, 0, stream>>>(Ua, Wa, ba, bua, h0, W_ih, W_hh, W1, W2,
                                             Uab, WihT, WhhT, wx, qb, W1T, W2T,
                                             ctx_raw, lsum);
    scores_ctx<<<dim3(4096), 256, 0, stream>>>(enc, Uab, qb, Va, bva, ctx_raw, lsum);
    decoder2<<<dim3(B), 512, 0, stream>>>(x, c0, ctx_raw, lsum, h0, WihT, WhhT,
                                          b_ih, b_hh, wx, W1T, b1, W2T, b2, W3, b3, out);
}

// Round 17
// 139.887 us; speedup vs baseline: 1.2503x; 1.0022x over previous
//
#include <hip/hip_runtime.h>
#include <math.h>

#define B 128
#define T 2048
#define H 200
#define G4 800    // 4*H
#define KP 224    // Uab row stride (bf16)
#define ESTR 224  // elds row stride (bf16) = KP (R0-proven)
#define ROWS 64   // t-rows per block

typedef short short8 __attribute__((ext_vector_type(8)));
typedef float floatx4 __attribute__((ext_vector_type(4)));

__device__ __forceinline__ unsigned short f2bf(float x) {
    unsigned u = __float_as_uint(x);
    return (unsigned short)((u + 0x7fffu + ((u >> 16) & 1u)) >> 16);
}
__device__ __forceinline__ float bf2f(unsigned short s) {
    return __uint_as_float(((unsigned)s) << 16);
}
// pack two floats -> two bf16 (round-nearest-away) in 3 VALU ops
__device__ __forceinline__ unsigned pk2(float a, float b) {
    return __builtin_amdgcn_perm(__float_as_uint(b) + 0x8000u,
                                 __float_as_uint(a) + 0x8000u, 0x07060302u);
}
// tanh(x) = 1 - 2/(exp(2x)+1), hw exp2 + rcp (~1e-6 rel err)
__device__ __forceinline__ float ftanh(float x) {
    float e = __builtin_amdgcn_exp2f(x * 2.885390081777927f);
    float r = __builtin_amdgcn_rcpf(e + 1.f);
    return fmaf(-2.f, r, 1.f);
}
__device__ __forceinline__ float sigm(float x) { return 1.f / (1.f + expf(-x)); }

// ---------------- prep_all ----------------
// blocks 0..255    : Uab row (bf16, zero-padded [256][224])
// blocks 256..455  : W_ihT[k][j] = W_ih[j][1+k]
// blocks 456..655  : W_hhT[k][j] = W_hh[j][k]
// block  656       : wx[j] = W_ih[j][0]
// blocks 657..784  : qb[b][h] = h0[b] @ Wa.T + ba + bua   (float4 dot)
// blocks 785..984  : W1T[k][j] = W1[j][k]   (k<200, j<100)
// blocks 985..1084 : W2T[k][j] = W2[j][k]   (k<100, j<50)
// blocks 1085..1184: ctx_raw zero (replaces the standalone hipMemsetAsync node)
// block  1185      : lsum zero
__global__ __launch_bounds__(256) void prep_all(const float* __restrict__ Ua,
                                                const float* __restrict__ Wa,
                                                const float* __restrict__ ba,
                                                const float* __restrict__ bua,
                                                const float* __restrict__ h0,
                                                const float* __restrict__ W_ih,
                                                const float* __restrict__ W_hh,
                                                const float* __restrict__ W1,
                                                const float* __restrict__ W2,
                                                unsigned short* __restrict__ Uab,
                                                float* __restrict__ WihT,
                                                float* __restrict__ WhhT,
                                                float* __restrict__ wx,
                                                float* __restrict__ qb,
                                                float* __restrict__ W1T,
                                                float* __restrict__ W2T,
                                                float* __restrict__ ctx_raw,
                                                float* __restrict__ lsum) {
    __shared__ __align__(16) float qs[H];
    int bx = blockIdx.x, tid = threadIdx.x;
    if (bx < 256) {
        if (tid < KP) {
            float v = (bx < H && tid < H) ? Ua[bx * H + tid] : 0.f;
            Uab[bx * KP + tid] = f2bf(v);
        }
    } else if (bx < 456) {
        int k = bx - 256;
        for (int j = tid; j < G4; j += 256) WihT[k * G4 + j] = W_ih[(size_t)j * (H + 1) + 1 + k];
    } else if (bx < 656) {
        int k = bx - 456;
        for (int j = tid; j < G4; j += 256) WhhT[k * G4 + j] = W_hh[(size_t)j * H + k];
    } else if (bx == 656) {
        for (int j = tid; j < G4; j += 256) wx[j] = W_ih[(size_t)j * (H + 1)];
    } else if (bx < 785) {
        int b = bx - 657;
        if (tid < H) qs[tid] = h0[b * H + tid];
        __syncthreads();
        if (tid < H) {
            float a = ba[tid] + bua[tid];
            const float4* w  = (const float4*)(Wa + tid * H);
            const float4* qv = (const float4*)qs;
            #pragma unroll 8
            for (int k = 0; k < 50; k++) {
                float4 wv = w[k], q4 = qv[k];
                a = fmaf(wv.x, q4.x, a);
                a = fmaf(wv.y, q4.y, a);
                a = fmaf(wv.z, q4.z, a);
                a = fmaf(wv.w, q4.w, a);
            }
            qb[b * H + tid] = a;
        }
    } else if (bx < 985) {
        int k = bx - 785;
        if (tid < 100) W1T[k * 100 + tid] = W1[tid * H + k];
    } else if (bx < 1085) {
        int k = bx - 985;
        if (tid < 50) W2T[k * 50 + tid] = W2[tid * 100 + k];
    } else if (bx < 1185) {
        ctx_raw[(bx - 1085) * 256 + tid] = 0.f;   // 100*256 = 25600 = B*H exactly
    } else {
        if (tid < B) lsum[tid] = 0.f;
    }
}

// ---------------- scores + bounded-softmax + context (R0 form + staged prefetch) ----------------
// CONVERGED session-best form (R12/R14/R15: 140.2 us total / ~136 us scores).
// The ONLY form measured spill-free at 64 VGPR across 16 rounds: rolled
// 2-iteration mig loop, af[2][7] reloaded per group from L2-hot Uab, 16 m-tiles
// (h up to 255; s_va/s_qb zero-padded to 256 annihilate h>=200), prefetch-by-1
// loop staging (<=2 float4 live). Measured invariants: VGPR 64, LDS 32,256 B,
// occ ~44%, WRITE ~3.3 MB (no spill), dur invariant to L3-residency ->
// latency-chain plateau. Measured dead ends: occupancy 43-81% (not the lever),
// DMA/double-buffer pipelining, 13-m-tile split, direct-global B, kernel split
// (forces 210 MB enc re-read). DO NOT perturb launch bounds, the rolled mig
// loop, or the staging form -- every variant flipped the allocator into spill
// (R1/R7/R9/R10) or af-sinking (R8/R13).

__global__ __launch_bounds__(256, 4) void scores_ctx(const float* __restrict__ enc,
                                                     const unsigned short* __restrict__ Uab,
                                                     const float* __restrict__ qb,
                                                     const float* __restrict__ Va,
                                                     const float* __restrict__ bva,
                                                     float* __restrict__ ctx_raw,
                                                     float* __restrict__ lsum) {
    __shared__ unsigned short elds[ROWS * ESTR];   // 28672 B
    __shared__ float s_qb[256];
    __shared__ float s_va[256];
    __shared__ float part[4][ROWS];
    __shared__ float wlds[ROWS];

    int bx  = blockIdx.x;
    int b   = bx >> 5;
    int t0  = (bx & 31) * ROWS;
    int tid = threadIdx.x, w = tid >> 6, lane = tid & 63, r = lane & 15, q = lane >> 4;

    // zero k-pad columns 200..223 (12 uints per row)
    for (int i = tid; i < ROWS * 12; i += 256) {
        int rr = i / 12, cc = i - rr * 12;
        *(unsigned*)(elds + rr * ESTR + 200 + 2 * cc) = 0u;
    }
    s_qb[tid] = (tid < H) ? qb[b * H + tid] : 0.f;
    s_va[tid] = (tid < H) ? Va[tid] : 0.f;
    float bv = bva[0];

    // stage enc[b, t0..t0+63, :] -> bf16 LDS, prefetch-by-1 (<=2 float4 live)
    const float4* src = (const float4*)(enc + (size_t)(b * T + t0) * H);
    float4 v = src[tid];
    for (int i = tid; i < ROWS * 50; i += 256) {
        float4 vn = v;
        int nxt = i + 256;
        if (nxt < ROWS * 50) vn = src[nxt];
        int rr = i / 50, cc = i - rr * 50;
        unsigned* dst = (unsigned*)(elds + rr * ESTR + cc * 4);
        dst[0] = pk2(v.x, v.y);
        dst[1] = pk2(v.z, v.w);
        v = vn;
    }
    __syncthreads();

    // scores: wave w owns m-tiles 4w..4w+3, processed as 2 groups of 2 (R0 form)
    float p[4] = {0.f, 0.f, 0.f, 0.f};
    for (int mig = 0; mig < 2; ++mig) {
        int m0 = w * 4 + mig * 2;
        short8 af[2][7];
        #pragma unroll
        for (int mi = 0; mi < 2; mi++)
            #pragma unroll
            for (int ks = 0; ks < 7; ks++)
                af[mi][ks] = *(const short8*)(Uab + ((m0 + mi) * 16 + r) * KP + ks * 32 + q * 8);

        #pragma unroll
        for (int nt = 0; nt < 4; nt++) {
            floatx4 C0 = (floatx4){0.f, 0.f, 0.f, 0.f};
            floatx4 C1 = (floatx4){0.f, 0.f, 0.f, 0.f};
            #pragma unroll
            for (int ks = 0; ks < 7; ks++) {
                short8 bf = *(const short8*)(elds + (nt * 16 + r) * ESTR + ks * 32 + q * 8);
                C0 = __builtin_amdgcn_mfma_f32_16x16x32_bf16(af[0][ks], bf, C0, 0, 0, 0);
                C1 = __builtin_amdgcn_mfma_f32_16x16x32_bf16(af[1][ks], bf, C1, 0, 0, 0);
            }
            float pp = 0.f;
            #pragma unroll
            for (int rg = 0; rg < 4; rg++) {
                int h0i = m0 * 16 + q * 4 + rg;
                int h1i = h0i + 16;
                pp += s_va[h0i] * ftanh(s_qb[h0i] + C0[rg]);
                pp += s_va[h1i] * ftanh(s_qb[h1i] + C1[rg]);
            }
            p[nt] += pp;
        }
    }
    #pragma unroll
    for (int nt = 0; nt < 4; nt++) {
        float pp = p[nt];
        pp += __shfl_xor(pp, 16);
        pp += __shfl_xor(pp, 32);
        if (q == 0) part[w][nt * 16 + r] = pp;
    }
    __syncthreads();

    if (w == 0) {   // wave 0: bound + softmax + lsum atomic
        float a = fabsf(s_va[lane]) + fabsf(s_va[lane + 64]) +
                  fabsf(s_va[lane + 128]) + fabsf(s_va[lane + 192]);
        #pragma unroll
        for (int d = 1; d < 64; d <<= 1) a += __shfl_xor(a, d);
        float bound = a + fabsf(bv);

        float s  = part[0][lane] + part[1][lane] + part[2][lane] + part[3][lane] + bv;
        float we = __builtin_amdgcn_exp2f((s - bound) * 1.4426950408889634f);
        wlds[lane] = we;
        #pragma unroll
        for (int d = 1; d < 64; d <<= 1) we += __shfl_xor(we, d);
        if (lane == 0) atomicAdd(&lsum[b], we);
    }
    __syncthreads();

    if (tid < H) {   // ctx[h] += sum_t w[t]*enc[t,h] from bf16 LDS
        float a0 = 0.f, a1 = 0.f, a2 = 0.f, a3 = 0.f;
        #pragma unroll 4
        for (int t = 0; t < ROWS; t += 4) {
            a0 = fmaf(wlds[t],     bf2f(elds[(t    ) * ESTR + tid]), a0);
            a1 = fmaf(wlds[t + 1], bf2f(elds[(t + 1) * ESTR + tid]), a1);
            a2 = fmaf(wlds[t + 2], bf2f(elds[(t + 2) * ESTR + tid]), a2);
            a3 = fmaf(wlds[t + 3], bf2f(elds[(t + 3) * ESTR + tid]), a3);
        }
        atomicAdd(&ctx_raw[b * H + tid], (a0 + a1) + (a2 + a3));
    }
}

// ---------------- decoder (fused gc prologue + 5 steps), 512 threads ----------------
__global__ __launch_bounds__(512) void decoder2(const float* __restrict__ x,
                                                const float* __restrict__ c0,
                                                const float* __restrict__ ctx_raw,
                                                const float* __restrict__ lsum,
                                                const float* __restrict__ h0,
                                                const float* __restrict__ WihT,
                                                const float* __restrict__ WhhT,
                                                const float* __restrict__ b_ih,
                                                const float* __restrict__ b_hh,
                                                const float* __restrict__ wx,
                                                const float* __restrict__ W1T,
                                                const float* __restrict__ b1,
                                                const float* __restrict__ W2T,
                                                const float* __restrict__ b2,
                                                const float* __restrict__ W3,
                                                const float* __restrict__ b3,
                                                float* __restrict__ out) {
    __shared__ float s_gc[G4];
    __shared__ float s_wx[G4];
    __shared__ float s_ctx[H];
    __shared__ float s_q[H];
    __shared__ float s_out[H];
    __shared__ float s_o1[100];
    __shared__ float s_o2[50];
    __shared__ float s_w3[64];
    __shared__ float s_x;
    int b = blockIdx.x, tid = threadIdx.x;

    if (tid < H) {
        float invl = 1.f / lsum[b];
        s_ctx[tid] = ctx_raw[b * H + tid] * invl;
        s_q[tid]   = h0[b * H + tid];
    }
    s_wx[tid] = wx[tid];
    if (tid < G4 - 512) s_wx[512 + tid] = wx[512 + tid];
    if (tid < 64) s_w3[tid] = (tid < 50) ? W3[tid] : 0.f;
    if (tid == 0) s_x = x[b];
    float b3v = b3[0];
    __syncthreads();

    // gc[j] = b_ih+b_hh + ctx.Wih[:,1:] + q.Whh   (two j per thread)
    {
        int j0 = tid;
        int j1 = 512 + ((tid < 288) ? tid : 287);
        float a0 = b_ih[j0] + b_hh[j0];
        float a1 = b_ih[j1] + b_hh[j1];
        #pragma unroll 4
        for (int k = 0; k < H; k++) {
            float cv = s_ctx[k], qv = s_q[k];
            a0 = fmaf(cv, WihT[k * G4 + j0], a0);
            a0 = fmaf(qv, WhhT[k * G4 + j0], a0);
            a1 = fmaf(cv, WihT[k * G4 + j1], a1);
            a1 = fmaf(qv, WhhT[k * G4 + j1], a1);
        }
        s_gc[j0] = a0;
        if (tid < 288) s_gc[512 + tid] = a1;
    }
    float cprev = (tid < H) ? c0[b * H + tid] : 0.f;
    __syncthreads();

    for (int s = 0; s < 5; s++) {
        float xv = s_x;
        if (tid < H) {
            float ig = s_gc[tid]         + xv * s_wx[tid];
            float fg = s_gc[H + tid]     + xv * s_wx[H + tid];
            float gg = s_gc[2 * H + tid] + xv * s_wx[2 * H + tid];
            float og = s_gc[3 * H + tid] + xv * s_wx[3 * H + tid];
            float c  = sigm(fg) * cprev + sigm(ig) * tanhf(gg);
            float hn = sigm(og) * tanhf(c);
            s_out[tid] = fmaxf(hn, 0.f);
        }
        __syncthreads();
        if (tid < 400) {   // W1: 4 lanes per output, k split 4x50
            int j = tid >> 2, q4 = tid & 3;
            float a = 0.f;
            const float* wp = W1T + (q4 * 50) * 100 + j;
            const float* op = s_out + q4 * 50;
            #pragma unroll 10
            for (int k = 0; k < 50; k++) a = fmaf(wp[k * 100], op[k], a);
            a += __shfl_xor(a, 1);
            a += __shfl_xor(a, 2);
            if (q4 == 0) s_o1[j] = fmaxf(a + b1[j], 0.f);
        }
        __syncthreads();
        if (tid < 200) {   // W2: 4 lanes per output, k split 4x25
            int j = tid >> 2, q4 = tid & 3;
            float a = 0.f;
            const float* wp = W2T + (q4 * 25) * 50 + j;
            const float* op = s_o1 + q4 * 25;
            #pragma unroll 5
            for (int k = 0; k < 25; k++) a = fmaf(wp[k * 50], op[k], a);
            a += __shfl_xor(a, 1);
            a += __shfl_xor(a, 2);
            if (q4 == 0) s_o2[j] = fmaxf(a + b2[j], 0.f);
        }
        __syncthreads();
        if (tid < 64) {   // W3: wave reduce
            float a = (tid < 50) ? s_w3[tid] * s_o2[tid] : 0.f;
            #pragma unroll
            for (int d = 1; d < 64; d <<= 1) a += __shfl_xor(a, d);
            if (tid == 0) {
                float y = a + b3v;
                out[b * 5 + s] = y;
                s_x = y;
            }
        }
        __syncthreads();
    }
}

// ---------------- launch ----------------
extern "C" void kernel_launch(void* const* d_in, const int* in_sizes, int n_in,
                              void* d_out, int out_size, void* d_ws, size_t ws_size,
                              hipStream_t stream) {
    (void)in_sizes; (void)n_in; (void)out_size; (void)ws_size;
    const float* x    = (const float*)d_in[0];
    const float* h0   = (const float*)d_in[1];
    const float* c0   = (const float*)d_in[2];
    const float* enc  = (const float*)d_in[3];
    const float* Wa   = (const float*)d_in[4];
    const float* ba   = (const float*)d_in[5];
    const float* Ua   = (const float*)d_in[6];
    const float* bua  = (const float*)d_in[7];
    const float* Va   = (const float*)d_in[8];
    const float* bva  = (const float*)d_in[9];
    const float* W_ih = (const float*)d_in[10];
    const float* W_hh = (const float*)d_in[11];
    const float* b_ih = (const float*)d_in[12];
    const float* b_hh = (const float*)d_in[13];
    const float* W1   = (const float*)d_in[14];
    const float* b1   = (const float*)d_in[15];
    const float* W2   = (const float*)d_in[16];
    const float* b2   = (const float*)d_in[17];
    const float* W3   = (const float*)d_in[18];
    const float* b3   = (const float*)d_in[19];
    float* out = (float*)d_out;

    char* ws = (char*)d_ws;
    unsigned short* Uab = (unsigned short*)(ws);   // 114688
    float* WihT    = (float*)(ws + 114688);        // 640000
    float* WhhT    = (float*)(ws + 754688);        // 640000
    float* wx      = (float*)(ws + 1394688);       // 3200
    float* qb      = (float*)(ws + 1397888);       // 102400
    float* W1T     = (float*)(ws + 1500288);       // 80000
    float* W2T     = (float*)(ws + 1580288);       // 20000
    float* ctx_raw = (float*)(ws + 1600288);       // 102400
    float* lsum    = (float*)(ws + 1702688);       // 512

    prep_all<<<dim3(1186), 256, 0, stream>>>(Ua, Wa, ba, bua, h0, W_ih, W_hh, W1, W2,
                                             Uab, WihT, WhhT, wx, qb, W1T, W2T,
                                             ctx_raw, lsum);
    scores_ctx<<<dim3(4096), 256, 0, stream>>>(enc, Uab, qb, Va, bva, ctx_raw, lsum);
    decoder2<<<dim3(B), 512, 0, stream>>>(x, c0, ctx_raw, lsum, h0, WihT, WhhT,
                                          b_ih, b_hh, wx, W1T, b1, W2T, b2, W3, b3, out);
}